// Round 8
// baseline (886.369 us; speedup 1.0000x reference)
//
#include <hip/hip_runtime.h>
#include <cstdint>
#include <cstddef>

#define WS_ALIGN(x) (((x) + 255) & ~(size_t)255)

#define CHUNK  4096     // edges per bucketing block
#define BSHIFT 8        // 256 nodes per bucket (= LDS gather window)
#define BNODES 256
#define MAXNB  512      // supports N <= 131072 (problem: N=50000 -> NB=196)

// ---------- pass A: per-block coarse histogram ----------
__global__ __launch_bounds__(256) void pA_hist(const int* __restrict__ dst, int* __restrict__ bh,
                                               int E, int NB, int NBLK) {
  __shared__ int hist[MAXNB];
  int t = threadIdx.x, blk = blockIdx.x;
  for (int b = t; b < NB; b += 256) hist[b] = 0;
  __syncthreads();
  int e0 = blk * CHUNK, e1 = min(E, e0 + CHUNK);
  for (int e = e0 + t; e < e1; e += 256) atomicAdd(&hist[dst[e] >> BSHIFT], 1);
  __syncthreads();
  for (int b = t; b < NB; b += 256) bh[b * NBLK + blk] = hist[b];   // bucket-major
}

// ---------- hierarchical exclusive scan of bh[M] -> scn[M] ----------
__global__ __launch_bounds__(256) void k_s1(const int* __restrict__ in, int* __restrict__ bsum, int M) {
  __shared__ int s[256];
  int t = threadIdx.x, i = blockIdx.x * 256 + t;
  s[t] = (i < M) ? in[i] : 0; __syncthreads();
  for (int d = 128; d > 0; d >>= 1) { if (t < d) s[t] += s[t + d]; __syncthreads(); }
  if (t == 0) bsum[blockIdx.x] = s[0];
}

__global__ __launch_bounds__(256) void k_s2(const int* __restrict__ bsum, int* __restrict__ boff, int nb) {
  int t = threadIdx.x;
  __shared__ int s[256];
  if (nb <= 256) {
    int v = (t < nb) ? bsum[t] : 0;
    s[t] = v; __syncthreads();
    for (int d = 1; d < 256; d <<= 1) {
      int add = (t >= d) ? s[t - d] : 0;
      __syncthreads(); s[t] += add; __syncthreads();
    }
    if (t < nb) boff[t] = s[t] - v;
  } else {
    if (t == 0) { int run = 0; for (int b = 0; b < nb; ++b) { boff[b] = run; run += bsum[b]; } }
  }
}

__global__ __launch_bounds__(256) void k_s3(const int* __restrict__ in, const int* __restrict__ boff,
                                            int* __restrict__ out, int M) {
  __shared__ int s[256];
  int t = threadIdx.x, i = blockIdx.x * 256 + t;
  int v = (i < M) ? in[i] : 0;
  s[t] = v; __syncthreads();
  for (int d = 1; d < 256; d <<= 1) {
    int add = (t >= d) ? s[t - d] : 0;
    __syncthreads(); s[t] += add; __syncthreads();
  }
  if (i < M) out[i] = s[t] - v + boff[blockIdx.x];
}

// ---------- pass C: bucket-sort each chunk in LDS, write (src,dst) runs contiguously ----------
__global__ __launch_bounds__(256) void pC_scatter(const int* __restrict__ ei, const int* __restrict__ scn,
                                                  int2* __restrict__ pairs, int E, int NB, int NBLK) {
  __shared__ int hist[MAXNB], gcur[MAXNB], cur[MAXNB], lscan[MAXNB + 1], inc[MAXNB];
  __shared__ unsigned short bmap[CHUNK];
  __shared__ int sSrc[CHUNK], sDst[CHUNK];
  int t = threadIdx.x, blk = blockIdx.x;
  for (int b = t; b < NB; b += 256) { hist[b] = 0; gcur[b] = scn[b * NBLK + blk]; }
  __syncthreads();
  int e0 = blk * CHUNK, e1 = min(E, e0 + CHUNK), cnt = e1 - e0;
  for (int e = e0 + t; e < e1; e += 256) atomicAdd(&hist[ei[E + e] >> BSHIFT], 1);
  __syncthreads();
  {
    inc[t] = (t < NB) ? hist[t] : 0;
    inc[t + 256] = (t + 256 < NB) ? hist[t + 256] : 0;
    __syncthreads();
    for (int d = 1; d < MAXNB; d <<= 1) {
      int a0 = (t >= d) ? inc[t - d] : 0;
      int a1 = (t + 256 >= d) ? inc[t + 256 - d] : 0;
      __syncthreads();
      inc[t] += a0; inc[t + 256] += a1;
      __syncthreads();
    }
    if (t == 0) lscan[0] = 0;
    lscan[t + 1] = inc[t];
    lscan[t + 257] = inc[t + 256];
    __syncthreads();
  }
  for (int b = t; b < NB; b += 256) {
    cur[b] = lscan[b];
    for (int s = lscan[b]; s < lscan[b + 1]; ++s) bmap[s] = (unsigned short)b;
  }
  __syncthreads();
  for (int e = e0 + t; e < e1; e += 256) {
    int srcv = ei[e], dstv = ei[E + e];
    int b = dstv >> BSHIFT;
    int p = atomicAdd(&cur[b], 1);
    sSrc[p] = srcv; sDst[p] = dstv;
  }
  __syncthreads();
  for (int s = t; s < cnt; s += 256) {
    int b = bmap[s];
    int g = gcur[b] + (s - lscan[b]);
    pairs[g] = make_int2(sSrc[s], sDst[s]);
  }
}

// ---------- pass D (lite): per-bucket in-degree -> dinv only (no sort, no perm) ----------
__global__ __launch_bounds__(256) void pD_dinv(const int2* __restrict__ pairs, const int* __restrict__ scn,
                                               float* __restrict__ dinv, int N, int E, int NB, int NBLK) {
  __shared__ int cnt[BNODES];
  int t = threadIdx.x, b = blockIdx.x;
  int node0 = b << BSHIFT;
  cnt[t] = 0;
  __syncthreads();
  int S = scn[b * NBLK];
  int T = (b + 1 < NB) ? scn[(b + 1) * NBLK] : E;
  for (int e = S + t; e < T; e += 256) atomicAdd(&cnt[pairs[e].y - node0], 1);
  __syncthreads();
  int node = node0 + t;
  if (node < N) dinv[node] = rsqrtf((float)cnt[t] + 1.0f);   // +1 self-loop
}

// ---------- GEMM v4 (verified R6): 256 threads, 64-row LDS tile, wave q owns cols [16q,16q+16) ----------
template<int K>
__global__ __launch_bounds__(256) void k_gemm_scale(const float* __restrict__ X, const float* __restrict__ W,
                                                    const float* __restrict__ dinv, float* __restrict__ O, int N) {
  __shared__ float Xs[64 * (K + 1)];
  const int t = threadIdx.x;
  const int r = t & 63;                                          // row within tile
  const int q = __builtin_amdgcn_readfirstlane(t >> 6);          // col group, wave-uniform
  const int row0 = blockIdx.x * 64;

  {
    const float4* __restrict__ Xg = (const float4*)(X + (size_t)row0 * K);
    const int rows = min(64, N - row0);
    const int valid4 = rows * (K / 4);
    const int total4 = 64 * (K / 4);
    for (int i = t; i < total4; i += 256) {
      float4 v = (i < valid4) ? Xg[i] : make_float4(0.f, 0.f, 0.f, 0.f);
      int rr = i / (K / 4), c4 = i % (K / 4);
      float* d = &Xs[rr * (K + 1) + c4 * 4];
      d[0] = v.x; d[1] = v.y; d[2] = v.z; d[3] = v.w;
    }
  }
  __syncthreads();

  float acc[16];
  #pragma unroll
  for (int j = 0; j < 16; ++j) acc[j] = 0.f;

  const float* __restrict__ xrow = Xs + r * (K + 1);
  const float* __restrict__ Wq = W + q * 16;
  #pragma unroll 4
  for (int k = 0; k < K; ++k) {
    float xv = xrow[k];                         // ds_read_b32, conflict-free (2-way = free)
    const float* __restrict__ wr = Wq + k * 64; // wave-uniform -> s_load_dwordx16
    #pragma unroll
    for (int j = 0; j < 16; ++j) acc[j] = fmaf(xv, wr[j], acc[j]);
  }

  int row = row0 + r;
  if (row < N) {
    float dv = dinv[row];
    float4* __restrict__ Og = (float4*)(O + (size_t)row * 64 + q * 16);
    #pragma unroll
    for (int j4 = 0; j4 < 4; ++j4)
      Og[j4] = make_float4(acc[4 * j4] * dv, acc[4 * j4 + 1] * dv,
                           acc[4 * j4 + 2] * dv, acc[4 * j4 + 3] * dv);
  }
}

// ---------- gather v2 (fixed): edge-parallel, per-bucket LDS accumulation ----------
// Block = bucket of 256 nodes, 1024 threads = 16 waves. acc[256][64] (64 KB) init with
// self-loop rows; waves stream pairs edge-parallel (lane = feature, 4 rows in flight),
// LDS atomicAdd into dst row; writeout fuses dinv scale + bias (+relu).
template<bool RELU>
__global__ __launch_bounds__(1024) void k_gather(const float* __restrict__ g, const int2* __restrict__ pairs,
                                                 const int* __restrict__ scn, const float* __restrict__ dinv,
                                                 const float* __restrict__ bias, float* __restrict__ z,
                                                 int N, int E, int NB, int NBLK) {
  __shared__ float acc[BNODES * 64];   // 64 KB
  const int t = threadIdx.x;
  const int b = blockIdx.x;
  const int node0 = b << BSHIFT;
  const int rows = min(BNODES, N - node0);
  const int S = scn[b * NBLK];
  const int T = (b + 1 < NB) ? scn[(b + 1) * NBLK] : E;

  {  // init: acc[row][:] = g[node0+row][:]  (self-loop term), coalesced float4
    const float4* __restrict__ g4 = (const float4*)(g + (size_t)node0 * 64);
    float4* __restrict__ a4 = (float4*)acc;
    const int valid4 = rows * 16;
    for (int i = t; i < BNODES * 16; i += 1024)
      a4[i] = (i < valid4) ? g4[i] : make_float4(0.f, 0.f, 0.f, 0.f);
  }
  __syncthreads();

  const int lane = t & 63, w = t >> 6;      // 16 waves
  const int quads = (T - S) >> 2;
  for (int qd = w; qd < quads; qd += 16) {
    int e = S + 4 * qd;
    int2 p0 = pairs[e], p1 = pairs[e + 1], p2 = pairs[e + 2], p3 = pairs[e + 3];
    float v0 = g[(size_t)p0.x * 64 + lane];
    float v1 = g[(size_t)p1.x * 64 + lane];
    float v2 = g[(size_t)p2.x * 64 + lane];
    float v3 = g[(size_t)p3.x * 64 + lane];
    atomicAdd(&acc[((p0.y - node0) << 6) + lane], v0);
    atomicAdd(&acc[((p1.y - node0) << 6) + lane], v1);
    atomicAdd(&acc[((p2.y - node0) << 6) + lane], v2);
    atomicAdd(&acc[((p3.y - node0) << 6) + lane], v3);
  }
  if (w == 0) {
    for (int e = S + 4 * quads; e < T; ++e) {
      int2 p = pairs[e];
      atomicAdd(&acc[((p.y - node0) << 6) + lane], g[(size_t)p.x * 64 + lane]);
    }
  }
  __syncthreads();

  const float4* __restrict__ b4 = (const float4*)bias;
  const float4* __restrict__ a4 = (const float4*)acc;
  for (int i = t; i < rows * 16; i += 1024) {
    int row = i >> 4, c4 = i & 15;
    float dv = dinv[node0 + row];
    float4 a = a4[i];
    float4 bb = b4[c4];
    float4 r = make_float4(fmaf(a.x, dv, bb.x), fmaf(a.y, dv, bb.y),
                           fmaf(a.z, dv, bb.z), fmaf(a.w, dv, bb.w));
    if (RELU) {
      r.x = fmaxf(r.x, 0.f); r.y = fmaxf(r.y, 0.f);
      r.z = fmaxf(r.z, 0.f); r.w = fmaxf(r.w, 0.f);
    }
    ((float4*)(z + (size_t)(node0 + row) * 64))[c4] = r;
  }
}

// ---------- decoder: block-cooperative, 64 edges/block, 4 waves = 4 feature-quarters ----------
__global__ __launch_bounds__(256) void k_decode_fused(
    const float* __restrict__ z, const int* __restrict__ eli,
    const float* __restrict__ P1, const float* __restrict__ pb1,
    const float* __restrict__ P2, const float* __restrict__ pb2,
    const float* __restrict__ P3, const float* __restrict__ pb3,
    float* __restrict__ out, int EL) {
  __shared__ float ef[64 * 65];
  __shared__ float hs[64 * 65];
  __shared__ float part[4 * 64];
  const int t = threadIdx.x;
  const int e0 = blockIdx.x * 64;
  {
    int el = t >> 2, p = t & 3;
    int e = e0 + el;
    int ec = (e < EL) ? e : (EL - 1);
    int u = eli[ec], v = eli[EL + ec];
    const float4* zu = (const float4*)(z + (size_t)u * 64 + p * 16);
    const float4* zv = (const float4*)(z + (size_t)v * 64 + p * 16);
    float* w = &ef[el * 65 + p * 16];
    #pragma unroll
    for (int i = 0; i < 4; ++i) {
      float4 a = zu[i], b = zv[i];
      w[4 * i + 0] = a.x * b.x; w[4 * i + 1] = a.y * b.y;
      w[4 * i + 2] = a.z * b.z; w[4 * i + 3] = a.w * b.w;
    }
  }
  __syncthreads();
  const int lane = t & 63;
  const int q = __builtin_amdgcn_readfirstlane(t >> 6);
  float acc[16];
  #pragma unroll
  for (int j = 0; j < 16; ++j) acc[j] = pb1[16 * q + j];
  for (int k = 0; k < 64; ++k) {
    float efk = ef[lane * 65 + k];
    const float* __restrict__ w = P1 + k * 64 + 16 * q;
    #pragma unroll
    for (int j = 0; j < 16; ++j) acc[j] = fmaf(efk, w[j], acc[j]);
  }
  #pragma unroll
  for (int j = 0; j < 16; ++j) hs[lane * 65 + 16 * q + j] = fmaxf(acc[j], 0.f);
  __syncthreads();
  #pragma unroll
  for (int j = 0; j < 16; ++j) acc[j] = pb2[16 * q + j];
  for (int k = 0; k < 64; ++k) {
    float hk = hs[lane * 65 + k];
    const float* __restrict__ w = P2 + k * 64 + 16 * q;
    #pragma unroll
    for (int j = 0; j < 16; ++j) acc[j] = fmaf(hk, w[j], acc[j]);
  }
  float r = 0.f;
  #pragma unroll
  for (int j = 0; j < 16; ++j) r = fmaf(fmaxf(acc[j], 0.f), P3[16 * q + j], r);
  part[q * 64 + lane] = r;
  __syncthreads();
  if (t < 64) {
    int e = e0 + t;
    if (e < EL)
      out[e] = ((part[t] + part[64 + t]) + (part[128 + t] + part[192 + t])) + pb3[0];
  }
}

// ---------- host ----------
extern "C" void kernel_launch(void* const* d_in, const int* in_sizes, int n_in,
                              void* d_out, int out_size, void* d_ws, size_t ws_size,
                              hipStream_t stream) {
  const float* x   = (const float*)d_in[0];
  const int*   ei  = (const int*)d_in[1];
  const int*   eli = (const int*)d_in[2];
  const float* W1  = (const float*)d_in[3];
  const float* b1  = (const float*)d_in[4];
  const float* W2  = (const float*)d_in[5];
  const float* b2  = (const float*)d_in[6];
  const float* P1  = (const float*)d_in[7];
  const float* pb1 = (const float*)d_in[8];
  const float* P2  = (const float*)d_in[9];
  const float* pb2 = (const float*)d_in[10];
  const float* P3  = (const float*)d_in[11];
  const float* pb3 = (const float*)d_in[12];
  float* out = (float*)d_out;

  const int N  = in_sizes[0] / 128;
  const int E  = in_sizes[1] / 2;
  const int EL = in_sizes[2] / 2;

  const int NB   = (N + BNODES - 1) >> BSHIFT;       // 196 buckets
  const int NBLK = (E + CHUNK - 1) / CHUNK;          // 196 edge chunks
  const int M    = NB * NBLK;                        // 38416
  const int nb2  = (M + 255) / 256;                  // 151

  char* w = (char*)d_ws;
  auto alloc = [&](size_t bytes) { char* p = w; w += WS_ALIGN(bytes); return p; };
  int*   bh    = (int*)  alloc((size_t)M * 4);
  int*   scn   = (int*)  alloc((size_t)M * 4);
  int*   bsum  = (int*)  alloc(1024 * 4);
  int*   boff  = (int*)  alloc(1024 * 4);
  int2*  pairs = (int2*) alloc((size_t)E * 8);
  float* dinv  = (float*)alloc((size_t)N * 4);
  float* bufA  = (float*)alloc((size_t)N * 64 * 4);
  float* bufB  = (float*)alloc((size_t)N * 64 * 4);

  hipLaunchKernelGGL(pA_hist,    dim3(NBLK), dim3(256), 0, stream, ei + E, bh, E, NB, NBLK);
  hipLaunchKernelGGL(k_s1,       dim3(nb2),  dim3(256), 0, stream, bh, bsum, M);
  hipLaunchKernelGGL(k_s2,       dim3(1),    dim3(256), 0, stream, bsum, boff, nb2);
  hipLaunchKernelGGL(k_s3,       dim3(nb2),  dim3(256), 0, stream, bh, boff, scn, M);
  hipLaunchKernelGGL(pC_scatter, dim3(NBLK), dim3(256), 0, stream, ei, scn, pairs, E, NB, NBLK);
  hipLaunchKernelGGL(pD_dinv,    dim3(NB),   dim3(256), 0, stream, pairs, scn, dinv, N, E, NB, NBLK);

  hipLaunchKernelGGL((k_gemm_scale<128>), dim3((N + 63) / 64), dim3(256), 0, stream, x, W1, dinv, bufA, N);
  hipLaunchKernelGGL((k_gather<true>),    dim3(NB), dim3(1024), 0, stream, bufA, pairs, scn, dinv, b1, bufB, N, E, NB, NBLK);
  hipLaunchKernelGGL((k_gemm_scale<64>),  dim3((N + 63) / 64), dim3(256), 0, stream, bufB, W2, dinv, bufA, N);
  hipLaunchKernelGGL((k_gather<false>),   dim3(NB), dim3(1024), 0, stream, bufA, pairs, scn, dinv, b2, bufB, N, E, NB, NBLK);
  hipLaunchKernelGGL(k_decode_fused, dim3((EL + 63) / 64), dim3(256), 0, stream,
                     bufB, eli, P1, pb1, P2, pb2, P3, pb3, out, EL);
}

// Round 9
// 300.840 us; speedup vs baseline: 2.9463x; 2.9463x over previous
//
#include <hip/hip_runtime.h>
#include <cstdint>
#include <cstddef>

#define WS_ALIGN(x) (((x) + 255) & ~(size_t)255)

#define CHUNK  4096     // edges per bucketing block
#define BSHIFT 9        // 512 nodes per coarse bucket
#define BNODES 512
#define MAXNB  512      // supports N <= 262144 (problem: N=50000 -> NB=98)
#define CAP    12288    // max edges per bucket staged in LDS (mean ~8163, sd ~90)

// ---------- pass A: per-block coarse histogram ----------
__global__ __launch_bounds__(256) void pA_hist(const int* __restrict__ dst, int* __restrict__ bh,
                                               int E, int NB, int NBLK) {
  __shared__ int hist[MAXNB];
  int t = threadIdx.x, blk = blockIdx.x;
  for (int b = t; b < NB; b += 256) hist[b] = 0;
  __syncthreads();
  int e0 = blk * CHUNK, e1 = min(E, e0 + CHUNK);
  for (int e = e0 + t; e < e1; e += 256) atomicAdd(&hist[dst[e] >> BSHIFT], 1);
  __syncthreads();
  for (int b = t; b < NB; b += 256) bh[b * NBLK + blk] = hist[b];   // bucket-major
}

// ---------- hierarchical exclusive scan of bh[M] -> scn[M] ----------
__global__ __launch_bounds__(256) void k_s1(const int* __restrict__ in, int* __restrict__ bsum, int M) {
  __shared__ int s[256];
  int t = threadIdx.x, i = blockIdx.x * 256 + t;
  s[t] = (i < M) ? in[i] : 0; __syncthreads();
  for (int d = 128; d > 0; d >>= 1) { if (t < d) s[t] += s[t + d]; __syncthreads(); }
  if (t == 0) bsum[blockIdx.x] = s[0];
}

__global__ __launch_bounds__(256) void k_s2(const int* __restrict__ bsum, int* __restrict__ boff, int nb) {
  int t = threadIdx.x;
  __shared__ int s[256];
  if (nb <= 256) {
    int v = (t < nb) ? bsum[t] : 0;
    s[t] = v; __syncthreads();
    for (int d = 1; d < 256; d <<= 1) {
      int add = (t >= d) ? s[t - d] : 0;
      __syncthreads(); s[t] += add; __syncthreads();
    }
    if (t < nb) boff[t] = s[t] - v;
  } else {
    if (t == 0) { int run = 0; for (int b = 0; b < nb; ++b) { boff[b] = run; run += bsum[b]; } }
  }
}

__global__ __launch_bounds__(256) void k_s3(const int* __restrict__ in, const int* __restrict__ boff,
                                            int* __restrict__ out, int M) {
  __shared__ int s[256];
  int t = threadIdx.x, i = blockIdx.x * 256 + t;
  int v = (i < M) ? in[i] : 0;
  s[t] = v; __syncthreads();
  for (int d = 1; d < 256; d <<= 1) {
    int add = (t >= d) ? s[t - d] : 0;
    __syncthreads(); s[t] += add; __syncthreads();
  }
  if (i < M) out[i] = s[t] - v + boff[blockIdx.x];
}

// ---------- pass C: bucket-sort each chunk in LDS, write (src,dst) runs contiguously ----------
__global__ __launch_bounds__(256) void pC_scatter(const int* __restrict__ ei, const int* __restrict__ scn,
                                                  int2* __restrict__ pairs, int E, int NB, int NBLK) {
  __shared__ int hist[MAXNB], gcur[MAXNB], cur[MAXNB], lscan[MAXNB + 1], inc[MAXNB];
  __shared__ unsigned short bmap[CHUNK];
  __shared__ int sSrc[CHUNK], sDst[CHUNK];
  int t = threadIdx.x, blk = blockIdx.x;
  for (int b = t; b < NB; b += 256) { hist[b] = 0; gcur[b] = scn[b * NBLK + blk]; }
  __syncthreads();
  int e0 = blk * CHUNK, e1 = min(E, e0 + CHUNK), cnt = e1 - e0;
  for (int e = e0 + t; e < e1; e += 256) atomicAdd(&hist[ei[E + e] >> BSHIFT], 1);
  __syncthreads();
  {
    inc[t] = (t < NB) ? hist[t] : 0;
    inc[t + 256] = (t + 256 < NB) ? hist[t + 256] : 0;
    __syncthreads();
    for (int d = 1; d < MAXNB; d <<= 1) {
      int a0 = (t >= d) ? inc[t - d] : 0;
      int a1 = (t + 256 >= d) ? inc[t + 256 - d] : 0;
      __syncthreads();
      inc[t] += a0; inc[t + 256] += a1;
      __syncthreads();
    }
    if (t == 0) lscan[0] = 0;
    lscan[t + 1] = inc[t];
    lscan[t + 257] = inc[t + 256];
    __syncthreads();
  }
  for (int b = t; b < NB; b += 256) {
    cur[b] = lscan[b];
    for (int s = lscan[b]; s < lscan[b + 1]; ++s) bmap[s] = (unsigned short)b;
  }
  __syncthreads();
  for (int e = e0 + t; e < e1; e += 256) {
    int srcv = ei[e], dstv = ei[E + e];
    int b = dstv >> BSHIFT;
    int p = atomicAdd(&cur[b], 1);
    sSrc[p] = srcv; sDst[p] = dstv;
  }
  __syncthreads();
  for (int s = t; s < cnt; s += 256) {
    int b = bmap[s];
    int g = gcur[b] + (s - lscan[b]);
    pairs[g] = make_int2(sSrc[s], sDst[s]);
  }
}

// ---------- pass D: per-bucket fine CSR (verified R2-R6): counts -> dinv -> off -> sorted perm ----------
__global__ __launch_bounds__(256) void pD_fine(const int2* __restrict__ pairs, const int* __restrict__ scn,
                                               int* __restrict__ perm, int* __restrict__ off,
                                               float* __restrict__ dinv, int N, int E, int NB, int NBLK) {
  __shared__ int ncnt[BNODES], ncur[BNODES];
  __shared__ int staged[CAP];
  int t = threadIdx.x, b = blockIdx.x;
  int node0 = b << BSHIFT;
  int S = scn[b * NBLK];
  int T = (b + 1 < NB) ? scn[(b + 1) * NBLK] : E;
  ncnt[t] = 0; ncnt[t + 256] = 0;
  __syncthreads();
  for (int e = S + t; e < T; e += 256) atomicAdd(&ncnt[pairs[e].y - node0], 1);
  __syncthreads();
  for (int l = t; l < BNODES; l += 256) {
    int node = node0 + l;
    if (node < N) dinv[node] = rsqrtf((float)ncnt[l] + 1.0f);   // +1 self-loop
  }
  for (int d = 1; d < BNODES; d <<= 1) {
    int a0 = (t >= d) ? ncnt[t - d] : 0;
    int a1 = (t + 256 >= d) ? ncnt[t + 256 - d] : 0;
    __syncthreads();
    ncnt[t] += a0; ncnt[t + 256] += a1;
    __syncthreads();
  }
  for (int l = t; l < BNODES; l += 256) {
    int excl = (l > 0) ? ncnt[l - 1] : 0;
    ncur[l] = excl;
    int node = node0 + l;
    if (node < N) off[node] = S + excl;
  }
  if (b == NB - 1 && t == 0) off[N] = E;
  __syncthreads();
  bool ok = (T - S) <= CAP;
  for (int e = S + t; e < T; e += 256) {
    int2 p = pairs[e];
    int pos = atomicAdd(&ncur[p.y - node0], 1);
    if (ok) staged[pos] = p.x;
    else    perm[S + pos] = p.x;
  }
  if (ok) {
    __syncthreads();
    for (int s = t; s < T - S; s += 256) perm[S + s] = staged[s];
  }
}

// ---------- GEMM v4 (verified R6): 256 threads, 64-row LDS tile, wave q owns cols [16q,16q+16) ----------
template<int K>
__global__ __launch_bounds__(256) void k_gemm_scale(const float* __restrict__ X, const float* __restrict__ W,
                                                    const float* __restrict__ dinv, float* __restrict__ O, int N) {
  __shared__ float Xs[64 * (K + 1)];
  const int t = threadIdx.x;
  const int r = t & 63;
  const int q = __builtin_amdgcn_readfirstlane(t >> 6);
  const int row0 = blockIdx.x * 64;
  {
    const float4* __restrict__ Xg = (const float4*)(X + (size_t)row0 * K);
    const int rows = min(64, N - row0);
    const int valid4 = rows * (K / 4);
    const int total4 = 64 * (K / 4);
    for (int i = t; i < total4; i += 256) {
      float4 v = (i < valid4) ? Xg[i] : make_float4(0.f, 0.f, 0.f, 0.f);
      int rr = i / (K / 4), c4 = i % (K / 4);
      float* d = &Xs[rr * (K + 1) + c4 * 4];
      d[0] = v.x; d[1] = v.y; d[2] = v.z; d[3] = v.w;
    }
  }
  __syncthreads();
  float acc[16];
  #pragma unroll
  for (int j = 0; j < 16; ++j) acc[j] = 0.f;
  const float* __restrict__ xrow = Xs + r * (K + 1);
  const float* __restrict__ Wq = W + q * 16;
  #pragma unroll 4
  for (int k = 0; k < K; ++k) {
    float xv = xrow[k];
    const float* __restrict__ wr = Wq + k * 64;
    #pragma unroll
    for (int j = 0; j < 16; ++j) acc[j] = fmaf(xv, wr[j], acc[j]);
  }
  int row = row0 + r;
  if (row < N) {
    float dv = dinv[row];
    float4* __restrict__ Og = (float4*)(O + (size_t)row * 64 + q * 16);
    #pragma unroll
    for (int j4 = 0; j4 < 4; ++j4)
      Og[j4] = make_float4(acc[4 * j4] * dv, acc[4 * j4 + 1] * dv,
                           acc[4 * j4 + 2] * dv, acc[4 * j4 + 3] * dv);
  }
}

// ---------- gather v3: segmented reduction over dst-sorted edges, no LDS, no per-edge atomics ----------
// Wave w owns edges [w*256, w*256+256). Binary-search off for the starting node, stream
// 8 rows in flight, running sum in registers, one global atomicAdd per segment (~17/wave).
__global__ __launch_bounds__(256) void k_gatherseg(const float* __restrict__ g, const int* __restrict__ off,
                                                   const int* __restrict__ perm, float* __restrict__ acc,
                                                   int N, int E) {
  const int lane = threadIdx.x & 63;
  const int w = (blockIdx.x << 2) + (threadIdx.x >> 6);
  int e0 = w << 8;
  if (e0 >= E) return;
  int e1 = min(E, e0 + 256);
  // largest n with off[n] <= e0
  int lo = 0, hi = N;
  while (lo < hi) { int mid = (lo + hi + 1) >> 1; if (off[mid] <= e0) lo = mid; else hi = mid - 1; }
  int n = lo;
  int nend = off[n + 1];
  float run = 0.f;
  int e = e0;
  #define GSTEP(i, vi)                                                              \
    if (e + (i) >= nend) {                                                          \
      atomicAdd(&acc[(size_t)n * 64 + lane], run); run = 0.f;                       \
      do { ++n; nend = off[n + 1]; } while (e + (i) >= nend);                       \
    }                                                                               \
    run += (vi);
  for (; e + 8 <= e1; e += 8) {
    int4 a = *(const int4*)(perm + e);
    int4 b = *(const int4*)(perm + e + 4);
    float v0 = g[(size_t)a.x * 64 + lane];
    float v1 = g[(size_t)a.y * 64 + lane];
    float v2 = g[(size_t)a.z * 64 + lane];
    float v3 = g[(size_t)a.w * 64 + lane];
    float v4 = g[(size_t)b.x * 64 + lane];
    float v5 = g[(size_t)b.y * 64 + lane];
    float v6 = g[(size_t)b.z * 64 + lane];
    float v7 = g[(size_t)b.w * 64 + lane];
    GSTEP(0, v0) GSTEP(1, v1) GSTEP(2, v2) GSTEP(3, v3)
    GSTEP(4, v4) GSTEP(5, v5) GSTEP(6, v6) GSTEP(7, v7)
  }
  for (; e < e1; ++e) {
    float v = g[(size_t)perm[e] * 64 + lane];
    GSTEP(0, v)
  }
  #undef GSTEP
  atomicAdd(&acc[(size_t)n * 64 + lane], run);
}

// ---------- finalize: z = (relu)(dinv[n]*(acc[n]+g[n]) + bias) ----------
template<bool RELU>
__global__ __launch_bounds__(256) void k_finalize(const float* __restrict__ acc, const float* __restrict__ g,
                                                  const float* __restrict__ dinv, const float* __restrict__ bias,
                                                  float* __restrict__ z, int N) {
  int i = blockIdx.x * 256 + threadIdx.x;      // indexes float4s, N*16 total
  if (i >= N * 16) return;
  int n = i >> 4, c4 = i & 15;
  float dv = dinv[n];
  float4 a = ((const float4*)acc)[i];
  float4 s = ((const float4*)g)[i];
  float4 bb = ((const float4*)bias)[c4];
  float4 r = make_float4(fmaf(a.x + s.x, dv, bb.x), fmaf(a.y + s.y, dv, bb.y),
                         fmaf(a.z + s.z, dv, bb.z), fmaf(a.w + s.w, dv, bb.w));
  if (RELU) {
    r.x = fmaxf(r.x, 0.f); r.y = fmaxf(r.y, 0.f);
    r.z = fmaxf(r.z, 0.f); r.w = fmaxf(r.w, 0.f);
  }
  ((float4*)z)[i] = r;
}

// ---------- decoder (verified R3-R6): 64 edges/block, 4 waves = 4 feature-quarters ----------
__global__ __launch_bounds__(256) void k_decode_fused(
    const float* __restrict__ z, const int* __restrict__ eli,
    const float* __restrict__ P1, const float* __restrict__ pb1,
    const float* __restrict__ P2, const float* __restrict__ pb2,
    const float* __restrict__ P3, const float* __restrict__ pb3,
    float* __restrict__ out, int EL) {
  __shared__ float ef[64 * 65];
  __shared__ float hs[64 * 65];
  __shared__ float part[4 * 64];
  const int t = threadIdx.x;
  const int e0 = blockIdx.x * 64;
  {
    int el = t >> 2, p = t & 3;
    int e = e0 + el;
    int ec = (e < EL) ? e : (EL - 1);
    int u = eli[ec], v = eli[EL + ec];
    const float4* zu = (const float4*)(z + (size_t)u * 64 + p * 16);
    const float4* zv = (const float4*)(z + (size_t)v * 64 + p * 16);
    float* w = &ef[el * 65 + p * 16];
    #pragma unroll
    for (int i = 0; i < 4; ++i) {
      float4 a = zu[i], b = zv[i];
      w[4 * i + 0] = a.x * b.x; w[4 * i + 1] = a.y * b.y;
      w[4 * i + 2] = a.z * b.z; w[4 * i + 3] = a.w * b.w;
    }
  }
  __syncthreads();
  const int lane = t & 63;
  const int q = __builtin_amdgcn_readfirstlane(t >> 6);
  float acc[16];
  #pragma unroll
  for (int j = 0; j < 16; ++j) acc[j] = pb1[16 * q + j];
  for (int k = 0; k < 64; ++k) {
    float efk = ef[lane * 65 + k];
    const float* __restrict__ w = P1 + k * 64 + 16 * q;
    #pragma unroll
    for (int j = 0; j < 16; ++j) acc[j] = fmaf(efk, w[j], acc[j]);
  }
  #pragma unroll
  for (int j = 0; j < 16; ++j) hs[lane * 65 + 16 * q + j] = fmaxf(acc[j], 0.f);
  __syncthreads();
  #pragma unroll
  for (int j = 0; j < 16; ++j) acc[j] = pb2[16 * q + j];
  for (int k = 0; k < 64; ++k) {
    float hk = hs[lane * 65 + k];
    const float* __restrict__ w = P2 + k * 64 + 16 * q;
    #pragma unroll
    for (int j = 0; j < 16; ++j) acc[j] = fmaf(hk, w[j], acc[j]);
  }
  float r = 0.f;
  #pragma unroll
  for (int j = 0; j < 16; ++j) r = fmaf(fmaxf(acc[j], 0.f), P3[16 * q + j], r);
  part[q * 64 + lane] = r;
  __syncthreads();
  if (t < 64) {
    int e = e0 + t;
    if (e < EL)
      out[e] = ((part[t] + part[64 + t]) + (part[128 + t] + part[192 + t])) + pb3[0];
  }
}

// ---------- host ----------
extern "C" void kernel_launch(void* const* d_in, const int* in_sizes, int n_in,
                              void* d_out, int out_size, void* d_ws, size_t ws_size,
                              hipStream_t stream) {
  const float* x   = (const float*)d_in[0];
  const int*   ei  = (const int*)d_in[1];
  const int*   eli = (const int*)d_in[2];
  const float* W1  = (const float*)d_in[3];
  const float* b1  = (const float*)d_in[4];
  const float* W2  = (const float*)d_in[5];
  const float* b2  = (const float*)d_in[6];
  const float* P1  = (const float*)d_in[7];
  const float* pb1 = (const float*)d_in[8];
  const float* P2  = (const float*)d_in[9];
  const float* pb2 = (const float*)d_in[10];
  const float* P3  = (const float*)d_in[11];
  const float* pb3 = (const float*)d_in[12];
  float* out = (float*)d_out;

  const int N  = in_sizes[0] / 128;
  const int E  = in_sizes[1] / 2;
  const int EL = in_sizes[2] / 2;

  const int NB   = (N + BNODES - 1) >> BSHIFT;       // 98 buckets
  const int NBLK = (E + CHUNK - 1) / CHUNK;          // 196 edge chunks
  const int M    = NB * NBLK;                        // 19208
  const int nb2  = (M + 255) / 256;                  // 76

  char* w = (char*)d_ws;
  auto alloc = [&](size_t bytes) { char* p = w; w += WS_ALIGN(bytes); return p; };
  int*   bh    = (int*)  alloc((size_t)M * 4);
  int*   scn   = (int*)  alloc((size_t)M * 4);
  int*   bsum  = (int*)  alloc(1024 * 4);
  int*   boff  = (int*)  alloc(1024 * 4);
  int2*  pairs = (int2*) alloc((size_t)E * 8);
  int*   perm  = (int*)  alloc((size_t)E * 4);
  int*   off   = (int*)  alloc(((size_t)N + 1) * 4);
  float* dinv  = (float*)alloc((size_t)N * 4);
  float* bufA  = (float*)alloc((size_t)N * 64 * 4);   // g (scaled h)
  float* bufB  = (float*)alloc((size_t)N * 64 * 4);   // z (layer output)
  float* bufC  = (float*)alloc((size_t)N * 64 * 4);   // gather accumulator

  const int gw  = (E + 255) / 256;                   // gather waves
  const int gbk = (gw + 3) / 4;                      // gather blocks (4 waves each)
  const int fbk = (N * 16 + 255) / 256;              // finalize blocks

  hipLaunchKernelGGL(pA_hist,    dim3(NBLK), dim3(256), 0, stream, ei + E, bh, E, NB, NBLK);
  hipLaunchKernelGGL(k_s1,       dim3(nb2),  dim3(256), 0, stream, bh, bsum, M);
  hipLaunchKernelGGL(k_s2,       dim3(1),    dim3(256), 0, stream, bsum, boff, nb2);
  hipLaunchKernelGGL(k_s3,       dim3(nb2),  dim3(256), 0, stream, bh, boff, scn, M);
  hipLaunchKernelGGL(pC_scatter, dim3(NBLK), dim3(256), 0, stream, ei, scn, pairs, E, NB, NBLK);
  hipLaunchKernelGGL(pD_fine,    dim3(NB),   dim3(256), 0, stream, pairs, scn, perm, off, dinv, N, E, NB, NBLK);

  // layer 1
  hipLaunchKernelGGL((k_gemm_scale<128>), dim3((N + 63) / 64), dim3(256), 0, stream, x, W1, dinv, bufA, N);
  hipMemsetAsync(bufC, 0, (size_t)N * 64 * 4, stream);
  hipLaunchKernelGGL(k_gatherseg,  dim3(gbk), dim3(256), 0, stream, bufA, off, perm, bufC, N, E);
  hipLaunchKernelGGL((k_finalize<true>), dim3(fbk), dim3(256), 0, stream, bufC, bufA, dinv, b1, bufB, N);
  // layer 2
  hipLaunchKernelGGL((k_gemm_scale<64>),  dim3((N + 63) / 64), dim3(256), 0, stream, bufB, W2, dinv, bufA, N);
  hipMemsetAsync(bufC, 0, (size_t)N * 64 * 4, stream);
  hipLaunchKernelGGL(k_gatherseg,  dim3(gbk), dim3(256), 0, stream, bufA, off, perm, bufC, N, E);
  hipLaunchKernelGGL((k_finalize<false>), dim3(fbk), dim3(256), 0, stream, bufC, bufA, dinv, b2, bufB, N);
  // decoder
  hipLaunchKernelGGL(k_decode_fused, dim3((EL + 63) / 64), dim3(256), 0, stream,
                     bufB, eli, P1, pb1, P2, pb2, P3, pb3, out, EL);
}